// Round 5
// baseline (268.912 us; speedup 1.0000x reference)
//
#include <hip/hip_runtime.h>
#include <hip/hip_bf16.h>

#define B_ 16
#define L_ 1024
#define D_ 768
#define H_ 4
#define C_ 256
#define E_ 8192
#define ET_ (E_ + L_)     // 9216 edges per graph incl. self loops
#define HC_ (H_ * C_)     // 1024
#define F_ (D_ + HC_)     // 1792
#define M_ (B_ * L_)      // 16384 total nodes
#define NEG_SLOPE 0.2f

typedef short bf16x8 __attribute__((ext_vector_type(8)));
typedef float f32x16 __attribute__((ext_vector_type(16)));
using bf16 = __hip_bfloat16;

struct bf16x4_s { bf16 x, y, z, w; };

// ---------------- async global->LDS, 16B per lane ----------------
__device__ __forceinline__ void async_copy16(const bf16* gsrc, bf16* ldst) {
  __builtin_amdgcn_global_load_lds(
      (const __attribute__((address_space(1))) unsigned int*)gsrc,
      (__attribute__((address_space(3))) unsigned int*)ldst, 16, 0, 0);
}

// ============ kernel 1: prep — CSR (LDS) + x cast + weight casts + cout + asd-zero ============
#define NB_CSR 16
#define NB_X (M_ * (D_ / 8) / 256)   // 6144: one 8-elem chunk per thread
#define NB_W 2112                     // (HC_*D_ + D_*F_)/4/256 float4 chunks
#define NB_CO 192                     // one WAVE per output o (768 outputs / 4 waves)
#define NB_Z 128                      // zero a_s|a_d (512 KB contiguous), one uint4/thread

__global__ __launch_bounds__(256)
void prep(const float* __restrict__ x, const int* __restrict__ ei,
          const float* __restrict__ Wg, const float* __restrict__ Wout,
          const float* __restrict__ bgat, const float* __restrict__ bout,
          bf16* __restrict__ xf, bf16* __restrict__ wg_bf, bf16* __restrict__ wout_bf,
          int* __restrict__ deg_g, int* __restrict__ offs_g, int* __restrict__ csr_src,
          float* __restrict__ cout, float* __restrict__ asd_zero)
{
  __shared__ int s_deg[L_];
  __shared__ int s_cur[L_];
  __shared__ int s_part[256];
  const int blk = blockIdx.x;
  const int t = threadIdx.x;

  if (blk < NB_CSR) {
    // ---- whole CSR for graph b in one block: count -> scan -> fill (LDS only) ----
    const int b = blk;
    const int* srcp = ei + (long)b * 2 * E_;
    const int* dstp = srcp + E_;
    for (int i = t; i < L_; i += 256) s_deg[i] = 0;
    __syncthreads();
    for (int e = t; e < ET_; e += 256) {
      int dst = (e < E_) ? dstp[e] : (e - E_);
      atomicAdd(&s_deg[dst], 1);
    }
    __syncthreads();
    int d0 = s_deg[t*4], d1 = s_deg[t*4+1], d2 = s_deg[t*4+2], d3 = s_deg[t*4+3];
    int tsum = d0 + d1 + d2 + d3;
    s_part[t] = tsum;
    __syncthreads();
    for (int o = 1; o < 256; o <<= 1) {
      int v = (t >= o) ? s_part[t - o] : 0;
      __syncthreads();
      s_part[t] += v;
      __syncthreads();
    }
    int run = s_part[t] - tsum;       // exclusive prefix
    int o0 = run, o1 = o0 + d0, o2 = o1 + d1, o3 = o2 + d2;
    s_cur[t*4] = o0; s_cur[t*4+1] = o1; s_cur[t*4+2] = o2; s_cur[t*4+3] = o3;
    int gb = b * L_ + t * 4;
    offs_g[gb] = o0; offs_g[gb+1] = o1; offs_g[gb+2] = o2; offs_g[gb+3] = o3;
    deg_g[gb] = d0; deg_g[gb+1] = d1; deg_g[gb+2] = d2; deg_g[gb+3] = d3;
    __syncthreads();
    int* csr_b = csr_src + (long)b * ET_;
    for (int e = t; e < ET_; e += 256) {
      int src = (e < E_) ? srcp[e] : (e - E_);
      int dst = (e < E_) ? dstp[e] : (e - E_);
      int slot = atomicAdd(&s_cur[dst], 1);
      csr_b[slot] = src;
    }
  } else if (blk < NB_CSR + NB_X) {
    // ---- x cast: one 8-elem chunk per thread into xf cols 0..767 ----
    int idx = (blk - NB_CSR) * 256 + t;
    int row = idx / (D_ / 8);
    int c8 = idx - row * (D_ / 8);
    const float4* src = (const float4*)(x + (long)row * D_ + c8 * 8);
    float4 v0 = src[0], v1 = src[1];
    bf16 o[8];
    o[0] = __float2bfloat16(v0.x); o[1] = __float2bfloat16(v0.y);
    o[2] = __float2bfloat16(v0.z); o[3] = __float2bfloat16(v0.w);
    o[4] = __float2bfloat16(v1.x); o[5] = __float2bfloat16(v1.y);
    o[6] = __float2bfloat16(v1.z); o[7] = __float2bfloat16(v1.w);
    *(uint4*)(xf + (long)row * F_ + c8 * 8) = *(const uint4*)o;
  } else if (blk < NB_CSR + NB_X + NB_W) {
    // ---- weight casts: Wg then Wout, one float4 per thread ----
    long na4 = (long)HC_ * D_ / 4;
    long nb4 = (long)D_ * F_ / 4;
    long i0 = (long)(blk - NB_CSR - NB_X) * 256 + t;
    long stride = (long)NB_W * 256;
    for (long i = i0; i < na4 + nb4; i += stride) {
      const float4 v = (i < na4) ? ((const float4*)Wg)[i] : ((const float4*)Wout)[i - na4];
      bf16x4_s o;
      o.x = __float2bfloat16(v.x);
      o.y = __float2bfloat16(v.y);
      o.z = __float2bfloat16(v.z);
      o.w = __float2bfloat16(v.w);
      if (i < na4) ((bf16x4_s*)wg_bf)[i] = o;
      else         ((bf16x4_s*)wout_bf)[i - na4] = o;
    }
  } else if (blk < NB_CSR + NB_X + NB_W + NB_CO) {
    // ---- cout[o] = b_out[o] + sum_j b_gat[j] * W_out[o, D_+j] — one wave per o ----
    const int lane = t & 63;
    const int wave = t >> 6;
    int o = (blk - NB_CSR - NB_X - NB_W) * 4 + wave;
    if (o < D_) {
      const float4* wrow = (const float4*)(Wout + (long)o * F_ + D_);  // 256 float4
      const float4* bg4  = (const float4*)bgat;
      float s = 0.f;
#pragma unroll
      for (int q = 0; q < 4; q++) {
        float4 w = wrow[lane * 4 + q];
        float4 g = bg4[lane * 4 + q];
        s += w.x * g.x + w.y * g.y + w.z * g.z + w.w * g.w;
      }
#pragma unroll
      for (int sh = 1; sh < 64; sh <<= 1) s += __shfl_xor(s, sh);
      if (lane == 0) cout[o] = bout[o] + s;
    }
  } else {
    // ---- zero a_s|a_d (contiguous 2*M_*H_ floats = 512 KB), one uint4 per thread ----
    int idx = (blk - NB_CSR - NB_X - NB_W - NB_CO) * 256 + t;
    ((uint4*)asd_zero)[idx] = uint4{0u, 0u, 0u, 0u};
  }
}

// ============ NT GEMM, 128x128 tile, BK=64, 32x32x16 MFMA (validated round-0 config) ============
// global_load_lds 16B staging (8 consecutive lanes = 128B contiguous of one row)
// + XOR swizzle of k-chunks applied on the GLOBAL address, compensated at ds_read.
// K stays a RUNTIME arg: the rolled K-loop's conservative vmcnt(0)-before-barrier is
// load-bearing for correctness (template-K full unroll raced previously — do not redo).
// NOTE (rounds 1-2): two ports of the 256^2 8-phase counted-vmcnt template were BOTH
// slower (63.6 / 68.5 µs vs 57 µs here) despite zero bank conflicts — the 8-phase
// overlap does not reproduce at this shape (m232 open quadrant). Keep this structure.
// Fragments: A row m=lane&31, k=(lane>>5)*8+j ; B^T row n=lane&31, same k.
// C/D (m74/m101): col=lane&31, row=(reg&3)+8*(reg>>2)+4*(lane>>5), reg in [0,16).
// DO_ASD (GEMM-2 only): epilogue also reduces a_s/a_d = h·att_{src,dst} per row for
// this block's head (BN=128 tile lies within ONE head: n0>>8), from the fp32 accs,
// via 32-lane shfl_xor col-reduce + one fp32 atomicAdd per (row,head) per half-tile.
// Replaces the standalone calc_asd dispatch (round-5 change).
#define BM 128
#define BN 128
#define BK 64

template <int OUT_BF16, int DO_ASD>
__global__ __launch_bounds__(256)
void gemm_nt_128(const bf16* __restrict__ A, int lda,
                 const bf16* __restrict__ Bm, int ldb,
                 void* __restrict__ Cm_, int ldc, int K,
                 const float* __restrict__ bias,
                 const float* __restrict__ att_s_g, const float* __restrict__ att_d_g,
                 float* __restrict__ a_s, float* __restrict__ a_d)
{
  __shared__ __align__(16) bf16 As[BM * BK];   // 16 KB
  __shared__ __align__(16) bf16 Bs[BN * BK];   // 16 KB
  const int t = threadIdx.x;
  const int lane = t & 63;
  const int wave = t >> 6;
  const long m0 = (long)blockIdx.x * BM;
  const long n0 = (long)blockIdx.y * BN;
  const int wm = (wave >> 1) * 64;
  const int wn = (wave & 1) * 64;
  const int lrow = lane & 31;
  const int kg = lane >> 5;          // 0..1: which 8-elem k block within 16

  const int sr_base = wave * 32;
  const int sr_lane = lane >> 3;     // 0..7 (8 consecutive lanes share a row)
  const int c8l = lane & 7;          // 0..7

  f32x16 acc[2][2] = {};

  for (int k0 = 0; k0 < K; k0 += BK) {
#pragma unroll
    for (int j = 0; j < 4; j++) {
      int r = sr_base + j * 8 + sr_lane;
      int col = k0 + ((c8l ^ (r & 7)) << 3);
      bf16* ldsA = As + (sr_base + j * 8) * BK;   // wave-uniform base
      bf16* ldsB = Bs + (sr_base + j * 8) * BK;
      async_copy16(A + (m0 + r) * lda + col, ldsA);
      async_copy16(Bm + (n0 + r) * ldb + col, ldsB);
    }
    __syncthreads();
#pragma unroll
    for (int ks = 0; ks < BK; ks += 16) {
      bf16x8 af[2], bfr[2];
#pragma unroll
      for (int i = 0; i < 2; i++) {
        int ra = wm + i * 32 + lrow;
        int ca = ((ks >> 3) + kg) ^ (ra & 7);
        af[i] = *(const bf16x8*)(As + ra * BK + ca * 8);
        int rb = wn + i * 32 + lrow;
        int cb = ((ks >> 3) + kg) ^ (rb & 7);
        bfr[i] = *(const bf16x8*)(Bs + rb * BK + cb * 8);
      }
#pragma unroll
      for (int i = 0; i < 2; i++)
#pragma unroll
        for (int j = 0; j < 2; j++)
          acc[i][j] = __builtin_amdgcn_mfma_f32_32x32x16_bf16(af[i], bfr[j], acc[i][j], 0, 0, 0);
    }
    __syncthreads();
  }

#pragma unroll
  for (int i = 0; i < 2; i++) {
#pragma unroll
    for (int j = 0; j < 2; j++) {
      long col = n0 + wn + j * 32 + lrow;
      float bv = bias ? bias[col] : 0.f;
#pragma unroll
      for (int reg = 0; reg < 16; reg++) {
        long row = m0 + wm + i * 32 + (reg & 3) + 8 * (reg >> 2) + 4 * kg;
        float v = acc[i][j][reg] + bv;
        if (OUT_BF16) ((bf16*)Cm_)[row * ldc + col] = __float2bfloat16(v);
        else          ((float*)Cm_)[row * ldc + col] = v;
      }
    }
  }

  if constexpr (DO_ASD) {
    // a_s[row,hd] += sum over this block's 128 cols of acc*att_src (fp32, pre-rounding)
    const int hd = (int)(n0 >> 8);            // head of this col-tile
    const int cb = (int)(n0 & 255);           // col base within head (0 or 128)
    float ws[2], wd[2];
#pragma unroll
    for (int j = 0; j < 2; j++) {
      int c = cb + wn + j * 32 + lrow;
      ws[j] = att_s_g[hd * C_ + c];
      wd[j] = att_d_g[hd * C_ + c];
    }
#pragma unroll
    for (int i = 0; i < 2; i++) {
#pragma unroll
      for (int reg = 0; reg < 16; reg++) {
        float ps = acc[i][0][reg] * ws[0] + acc[i][1][reg] * ws[1];
        float pd = acc[i][0][reg] * wd[0] + acc[i][1][reg] * wd[1];
#pragma unroll
        for (int m = 1; m < 32; m <<= 1) { ps += __shfl_xor(ps, m); pd += __shfl_xor(pd, m); }
        if (lrow == 0) {
          long row = m0 + wm + i * 32 + (reg & 3) + 8 * (reg >> 2) + 4 * kg;
          atomicAdd(a_s + row * H_ + hd, ps);
          atomicAdd(a_d + row * H_ + hd, pd);
        }
      }
    }
  }
}

// ---------------- bf16 unpack helpers ----------------
__device__ __forceinline__ void unpack8(uint4 u0, float* f) {
#pragma unroll
  for (int k = 0; k < 4; k++) {
    unsigned w = ((const unsigned*)&u0)[k];
    f[2 * k]     = __uint_as_float(w << 16);
    f[2 * k + 1] = __uint_as_float(w & 0xffff0000u);
  }
}

// ============ fused aggregate: TWO WAVES per (b,dst) — each covers 512 channels ============
// Round-5 split: halves the per-wave serial gather chain (16B/lane/edge instead of 32B)
// and the VGPR footprint -> 2x TLP for latency hiding. p = exp(lrelu(a_s[src]+a_d[dst]))
// is recomputed per wave (cheap, head-uniform per 32-lane group).
__device__ inline float lrelu(float v) { return v > 0.f ? v : NEG_SLOPE * v; }

__global__ __launch_bounds__(256)
void gat_aggregate(const int* __restrict__ offs, const int* __restrict__ deg_a,
                   const int* __restrict__ csr_src,
                   const float* __restrict__ a_s, const float* __restrict__ a_d,
                   const bf16* __restrict__ h, bf16* __restrict__ xg, int ldx)
{
  const int t = threadIdx.x;
  const int lane = t & 63;
  const int wave = t >> 6;
  const int ds = wave >> 1;            // 0..1: which dst in this block
  const int half = wave & 1;           // 0..1: which 512-channel half
  // XCD swizzle: graph b pinned to XCD b%8 (2 graphs = 4MB h per XCD L2)
  const int i = blockIdx.x;            // M_/2 blocks = 8 (xcd) x 512 (grp) x 2 (hi)
  const int b = (i & 7) + 8 * ((i >> 3) >> 9);
  const int grp = (i >> 3) & 511;
  const int bd = b * L_ + grp * 2 + ds;
  const int deg = deg_a[bd];
  const int* list = csr_src + (long)b * ET_ + offs[bd];
  const int c0 = half * 512 + lane * 8;  // my 8 channels
  const int hd = c0 >> 8;                // my head

  const float ad = a_d[(long)bd * H_ + hd];
  const float* asb = a_s + (long)b * L_ * H_ + hd;   // graph-local rebase

  float acc[8];
#pragma unroll
  for (int k = 0; k < 8; k++) acc[k] = 0.f;
  float ssum = 0.f;
  const bf16* hb = h + (long)b * L_ * HC_ + c0;

  if (deg <= 64) {
    int s_lane = (lane < deg) ? list[lane] : 0;
#pragma unroll 4
    for (int e = 0; e < deg; e++) {
      int se = __shfl(s_lane, e);
      uint4 u0 = *(const uint4*)(hb + (long)se * HC_);
      float as = asb[(long)se * H_];
      float p = __expf(lrelu(as + ad));
      float f[8];
      unpack8(u0, f);
      ssum += p;
#pragma unroll
      for (int k = 0; k < 8; k++) acc[k] += p * f[k];
    }
  } else {
    for (int e = 0; e < deg; e++) {
      int se = list[e];
      uint4 u0 = *(const uint4*)(hb + (long)se * HC_);
      float as = asb[(long)se * H_];
      float p = __expf(lrelu(as + ad));
      float f[8];
      unpack8(u0, f);
      ssum += p;
#pragma unroll
      for (int k = 0; k < 8; k++) acc[k] += p * f[k];
    }
  }

  float rs = 1.f / (ssum + 1e-16f);
  bf16 ov[8];
#pragma unroll
  for (int k = 0; k < 8; k++) ov[k] = __float2bfloat16(acc[k] * rs);
  bf16* op = xg + (long)bd * ldx + c0;
  *(uint4*)op = *(const uint4*)ov;
}

// ---------------- launch ----------------
extern "C" void kernel_launch(void* const* d_in, const int* in_sizes, int n_in,
                              void* d_out, int out_size, void* d_ws, size_t ws_size,
                              hipStream_t stream) {
  const float* x     = (const float*)d_in[0];
  const int*   ei    = (const int*)d_in[1];
  const float* Wg    = (const float*)d_in[2];
  const float* att_s = (const float*)d_in[3];
  const float* att_d = (const float*)d_in[4];
  const float* bgat  = (const float*)d_in[5];
  const float* Wout  = (const float*)d_in[6];
  const float* bout  = (const float*)d_in[7];
  float* out = (float*)d_out;

  char* ws = (char*)d_ws;
  size_t off = 0;
  auto alloc = [&](size_t bytes) {
    void* p = ws + off;
    off = (off + bytes + 255) & ~(size_t)255;
    return p;
  };
  bf16* xf      = (bf16*)alloc((size_t)M_ * F_ * 2);       // 56 MB: [x | xg] bf16
  bf16* wg_bf   = (bf16*)alloc((size_t)HC_ * D_ * 2);
  bf16* wout_bf = (bf16*)alloc((size_t)D_ * F_ * 2);
  bf16* h_bf    = (bf16*)alloc((size_t)M_ * HC_ * 2);      // 32 MB
  int* deg      = (int*)alloc((size_t)M_ * 4);
  int* offs     = (int*)alloc((size_t)M_ * 4);
  int* csr_src  = (int*)alloc((size_t)B_ * ET_ * 4);
  float* cout   = (float*)alloc((size_t)D_ * 4);
  float* a_s    = (float*)alloc((size_t)M_ * H_ * 4);      // 256 KB  (contiguous with a_d —
  float* a_d    = (float*)alloc((size_t)M_ * H_ * 4);      //  256 KB  zeroed as one 512 KB range)

  // 1. prep: CSR + x cast + weight casts + cout + a_s/a_d zero — one dispatch
  prep<<<dim3(NB_CSR + NB_X + NB_W + NB_CO + NB_Z), dim3(256), 0, stream>>>(
      x, ei, Wg, Wout, bgat, bout, xf, wg_bf, wout_bf, deg, offs, csr_src, cout, a_s);

  // 2. h = x @ Wg^T (bf16 out) + fused a_s/a_d epilogue — 128 x 8 = 1024 blocks
  gemm_nt_128<1, 1><<<dim3(M_ / BM, HC_ / BN), dim3(256), 0, stream>>>(
      xf, F_, wg_bf, D_, h_bf, HC_, D_, nullptr, att_s, att_d, a_s, a_d);

  // 3. fused softmax + aggregate (2 waves per node), writes xg columns of xf
  gat_aggregate<<<dim3(M_ / 2), dim3(256), 0, stream>>>(offs, deg, csr_src,
                                                        a_s, a_d, h_bf, xf + D_, F_);

  // 4. out = [x|xg] @ W_out^T + cout   (single K=1792 GEMM) — 128 x 6 = 768 blocks
  gemm_nt_128<0, 0><<<dim3(M_ / BM, D_ / BN), dim3(256), 0, stream>>>(
      xf, F_, wout_bf, F_, out, D_, F_, cout, nullptr, nullptr, nullptr, nullptr);
}

// Round 6
// 256.720 us; speedup vs baseline: 1.0475x; 1.0475x over previous
//
#include <hip/hip_runtime.h>
#include <hip/hip_bf16.h>

#define B_ 16
#define L_ 1024
#define D_ 768
#define H_ 4
#define C_ 256
#define E_ 8192
#define ET_ (E_ + L_)     // 9216 edges per graph incl. self loops
#define HC_ (H_ * C_)     // 1024
#define F_ (D_ + HC_)     // 1792
#define M_ (B_ * L_)      // 16384 total nodes
#define NEG_SLOPE 0.2f

typedef short bf16x8 __attribute__((ext_vector_type(8)));
typedef float f32x16 __attribute__((ext_vector_type(16)));
using bf16 = __hip_bfloat16;

struct bf16x4_s { bf16 x, y, z, w; };

// ---------------- async global->LDS, 16B per lane ----------------
__device__ __forceinline__ void async_copy16(const bf16* gsrc, bf16* ldst) {
  __builtin_amdgcn_global_load_lds(
      (const __attribute__((address_space(1))) unsigned int*)gsrc,
      (__attribute__((address_space(3))) unsigned int*)ldst, 16, 0, 0);
}

// ============ kernel 1: prep — CSR (LDS) + x cast + weight casts + cout ============
#define NB_CSR 16
#define NB_X (M_ * (D_ / 8) / 256)   // 6144: one 8-elem chunk per thread
#define NB_W 2112                     // (HC_*D_ + D_*F_)/4/256 float4 chunks
#define NB_CO 192                     // one WAVE per output o (768 outputs / 4 waves)

__global__ __launch_bounds__(256)
void prep(const float* __restrict__ x, const int* __restrict__ ei,
          const float* __restrict__ Wg, const float* __restrict__ Wout,
          const float* __restrict__ bgat, const float* __restrict__ bout,
          bf16* __restrict__ xf, bf16* __restrict__ wg_bf, bf16* __restrict__ wout_bf,
          int* __restrict__ deg_g, int* __restrict__ offs_g, int* __restrict__ csr_src,
          float* __restrict__ cout)
{
  __shared__ int s_deg[L_];
  __shared__ int s_cur[L_];
  __shared__ int s_part[256];
  const int blk = blockIdx.x;
  const int t = threadIdx.x;

  if (blk < NB_CSR) {
    // ---- whole CSR for graph b in one block: count -> scan -> fill (LDS only) ----
    const int b = blk;
    const int* srcp = ei + (long)b * 2 * E_;
    const int* dstp = srcp + E_;
    for (int i = t; i < L_; i += 256) s_deg[i] = 0;
    __syncthreads();
    for (int e = t; e < ET_; e += 256) {
      int dst = (e < E_) ? dstp[e] : (e - E_);
      atomicAdd(&s_deg[dst], 1);
    }
    __syncthreads();
    int d0 = s_deg[t*4], d1 = s_deg[t*4+1], d2 = s_deg[t*4+2], d3 = s_deg[t*4+3];
    int tsum = d0 + d1 + d2 + d3;
    s_part[t] = tsum;
    __syncthreads();
    for (int o = 1; o < 256; o <<= 1) {
      int v = (t >= o) ? s_part[t - o] : 0;
      __syncthreads();
      s_part[t] += v;
      __syncthreads();
    }
    int run = s_part[t] - tsum;       // exclusive prefix
    int o0 = run, o1 = o0 + d0, o2 = o1 + d1, o3 = o2 + d2;
    s_cur[t*4] = o0; s_cur[t*4+1] = o1; s_cur[t*4+2] = o2; s_cur[t*4+3] = o3;
    int gb = b * L_ + t * 4;
    offs_g[gb] = o0; offs_g[gb+1] = o1; offs_g[gb+2] = o2; offs_g[gb+3] = o3;
    deg_g[gb] = d0; deg_g[gb+1] = d1; deg_g[gb+2] = d2; deg_g[gb+3] = d3;
    __syncthreads();
    int* csr_b = csr_src + (long)b * ET_;
    for (int e = t; e < ET_; e += 256) {
      int src = (e < E_) ? srcp[e] : (e - E_);
      int dst = (e < E_) ? dstp[e] : (e - E_);
      int slot = atomicAdd(&s_cur[dst], 1);
      csr_b[slot] = src;
    }
  } else if (blk < NB_CSR + NB_X) {
    // ---- x cast: one 8-elem chunk per thread into xf cols 0..767 ----
    int idx = (blk - NB_CSR) * 256 + t;
    int row = idx / (D_ / 8);
    int c8 = idx - row * (D_ / 8);
    const float4* src = (const float4*)(x + (long)row * D_ + c8 * 8);
    float4 v0 = src[0], v1 = src[1];
    bf16 o[8];
    o[0] = __float2bfloat16(v0.x); o[1] = __float2bfloat16(v0.y);
    o[2] = __float2bfloat16(v0.z); o[3] = __float2bfloat16(v0.w);
    o[4] = __float2bfloat16(v1.x); o[5] = __float2bfloat16(v1.y);
    o[6] = __float2bfloat16(v1.z); o[7] = __float2bfloat16(v1.w);
    *(uint4*)(xf + (long)row * F_ + c8 * 8) = *(const uint4*)o;
  } else if (blk < NB_CSR + NB_X + NB_W) {
    // ---- weight casts: Wg then Wout, one float4 per thread ----
    long na4 = (long)HC_ * D_ / 4;
    long nb4 = (long)D_ * F_ / 4;
    long i0 = (long)(blk - NB_CSR - NB_X) * 256 + t;
    long stride = (long)NB_W * 256;
    for (long i = i0; i < na4 + nb4; i += stride) {
      const float4 v = (i < na4) ? ((const float4*)Wg)[i] : ((const float4*)Wout)[i - na4];
      bf16x4_s o;
      o.x = __float2bfloat16(v.x);
      o.y = __float2bfloat16(v.y);
      o.z = __float2bfloat16(v.z);
      o.w = __float2bfloat16(v.w);
      if (i < na4) ((bf16x4_s*)wg_bf)[i] = o;
      else         ((bf16x4_s*)wout_bf)[i - na4] = o;
    }
  } else {
    // ---- cout[o] = b_out[o] + sum_j b_gat[j] * W_out[o, D_+j] — one wave per o ----
    const int lane = t & 63;
    const int wave = t >> 6;
    int o = (blk - NB_CSR - NB_X - NB_W) * 4 + wave;
    if (o < D_) {
      const float4* wrow = (const float4*)(Wout + (long)o * F_ + D_);  // 256 float4
      const float4* bg4  = (const float4*)bgat;
      float s = 0.f;
#pragma unroll
      for (int q = 0; q < 4; q++) {
        float4 w = wrow[lane * 4 + q];
        float4 g = bg4[lane * 4 + q];
        s += w.x * g.x + w.y * g.y + w.z * g.z + w.w * g.w;
      }
#pragma unroll
      for (int sh = 1; sh < 64; sh <<= 1) s += __shfl_xor(s, sh);
      if (lane == 0) cout[o] = bout[o] + s;
    }
  }
}

// ============ NT GEMM, 128x128 tile, BK=64, 32x32x16 MFMA (validated round-0 config) ============
// global_load_lds 16B staging + XOR swizzle on the GLOBAL address, compensated at ds_read.
// K stays a RUNTIME arg (template-K full unroll raced previously — do not redo).
// NOTE (rounds 1-2): two ports of the 256^2 8-phase counted-vmcnt template were BOTH
// slower (63.6 / 68.5 µs vs 57 µs) despite zero bank conflicts — keep this structure.
// NOTE (round 5): fusing the a_s/a_d reduction into this epilogue (shfl chains +
// device atomics) cost +41 µs (74 µs, MfmaUtil 13%) — do not redo. calc_asd stays
// a standalone kernel.
// Fragments: A row m=lane&31, k=(lane>>5)*8+j ; B^T row n=lane&31, same k.
// C/D (m74/m101): col=lane&31, row=(reg&3)+8*(reg>>2)+4*(lane>>5), reg in [0,16).
#define BM 128
#define BN 128
#define BK 64

template <int OUT_BF16>
__global__ __launch_bounds__(256)
void gemm_nt_128(const bf16* __restrict__ A, int lda,
                 const bf16* __restrict__ Bm, int ldb,
                 void* __restrict__ Cm_, int ldc, int K,
                 const float* __restrict__ bias)
{
  __shared__ __align__(16) bf16 As[BM * BK];   // 16 KB
  __shared__ __align__(16) bf16 Bs[BN * BK];   // 16 KB
  const int t = threadIdx.x;
  const int lane = t & 63;
  const int wave = t >> 6;
  const long m0 = (long)blockIdx.x * BM;
  const long n0 = (long)blockIdx.y * BN;
  const int wm = (wave >> 1) * 64;
  const int wn = (wave & 1) * 64;
  const int lrow = lane & 31;
  const int kg = lane >> 5;          // 0..1: which 8-elem k block within 16

  const int sr_base = wave * 32;
  const int sr_lane = lane >> 3;     // 0..7 (8 consecutive lanes share a row)
  const int c8l = lane & 7;          // 0..7

  f32x16 acc[2][2] = {};

  for (int k0 = 0; k0 < K; k0 += BK) {
#pragma unroll
    for (int j = 0; j < 4; j++) {
      int r = sr_base + j * 8 + sr_lane;
      int col = k0 + ((c8l ^ (r & 7)) << 3);
      bf16* ldsA = As + (sr_base + j * 8) * BK;   // wave-uniform base
      bf16* ldsB = Bs + (sr_base + j * 8) * BK;
      async_copy16(A + (m0 + r) * lda + col, ldsA);
      async_copy16(Bm + (n0 + r) * ldb + col, ldsB);
    }
    __syncthreads();
#pragma unroll
    for (int ks = 0; ks < BK; ks += 16) {
      bf16x8 af[2], bfr[2];
#pragma unroll
      for (int i = 0; i < 2; i++) {
        int ra = wm + i * 32 + lrow;
        int ca = ((ks >> 3) + kg) ^ (ra & 7);
        af[i] = *(const bf16x8*)(As + ra * BK + ca * 8);
        int rb = wn + i * 32 + lrow;
        int cb = ((ks >> 3) + kg) ^ (rb & 7);
        bfr[i] = *(const bf16x8*)(Bs + rb * BK + cb * 8);
      }
#pragma unroll
      for (int i = 0; i < 2; i++)
#pragma unroll
        for (int j = 0; j < 2; j++)
          acc[i][j] = __builtin_amdgcn_mfma_f32_32x32x16_bf16(af[i], bfr[j], acc[i][j], 0, 0, 0);
    }
    __syncthreads();
  }

#pragma unroll
  for (int i = 0; i < 2; i++) {
#pragma unroll
    for (int j = 0; j < 2; j++) {
      long col = n0 + wn + j * 32 + lrow;
      float bv = bias ? bias[col] : 0.f;
#pragma unroll
      for (int reg = 0; reg < 16; reg++) {
        long row = m0 + wm + i * 32 + (reg & 3) + 8 * (reg >> 2) + 4 * kg;
        float v = acc[i][j][reg] + bv;
        if (OUT_BF16) ((bf16*)Cm_)[row * ldc + col] = __float2bfloat16(v);
        else          ((float*)Cm_)[row * ldc + col] = v;
      }
    }
  }
}

// ---------------- bf16 unpack helpers ----------------
__device__ __forceinline__ void unpack16(uint4 u0, uint4 u1, float* f) {
#pragma unroll
  for (int k = 0; k < 4; k++) {
    unsigned w = ((const unsigned*)&u0)[k];
    f[2 * k]     = __uint_as_float(w << 16);
    f[2 * k + 1] = __uint_as_float(w & 0xffff0000u);
    unsigned w2 = ((const unsigned*)&u1)[k];
    f[8 + 2 * k]     = __uint_as_float(w2 << 16);
    f[8 + 2 * k + 1] = __uint_as_float(w2 & 0xffff0000u);
  }
}

__device__ __forceinline__ void unpack8(uint4 u0, float* f) {
#pragma unroll
  for (int k = 0; k < 4; k++) {
    unsigned w = ((const unsigned*)&u0)[k];
    f[2 * k]     = __uint_as_float(w << 16);
    f[2 * k + 1] = __uint_as_float(w & 0xffff0000u);
  }
}

// ============ calc_asd: a_s[n,h] = h[n]·att_src[h], a_d[n,h] = h[n]·att_dst[h] ============
// One wave per node (n = GLOBAL node index). Standalone kernel — measured cheap
// (round 4); fusing into GEMM-2's epilogue cost +41 µs (round 5, atomics+shfl).
__global__ __launch_bounds__(256)
void calc_asd(const bf16* __restrict__ h,
              const float* __restrict__ att_s_g, const float* __restrict__ att_d_g,
              float* __restrict__ a_s, float* __restrict__ a_d)
{
  const int t = threadIdx.x;
  const int lane = t & 63;
  const int wave = t >> 6;
  const int n = blockIdx.x * 4 + wave;
  const int c0 = lane * 16;

  float as16[16], ad16[16];
#pragma unroll
  for (int q = 0; q < 4; q++) {
    *(float4*)(as16 + 4 * q) = *(const float4*)(att_s_g + c0 + 4 * q);
    *(float4*)(ad16 + 4 * q) = *(const float4*)(att_d_g + c0 + 4 * q);
  }
  const bf16* hp = h + (long)n * HC_ + c0;
  float f[16];
  unpack16(*(const uint4*)hp, *(const uint4*)(hp + 8), f);
  float vs = 0.f, vd = 0.f;
#pragma unroll
  for (int k = 0; k < 16; k++) { vs += f[k] * as16[k]; vd += f[k] * ad16[k]; }
#pragma unroll
  for (int o = 1; o < 16; o <<= 1) { vs += __shfl_xor(vs, o); vd += __shfl_xor(vd, o); }
  if ((lane & 15) == 0) {
    int hd = lane >> 4;
    a_s[(long)n * H_ + hd] = vs;
    a_d[(long)n * H_ + hd] = vd;
  }
}

// ============ fused aggregate: TWO WAVES per (b,dst) — each covers 512 channels ============
// Round-5 split (KEPT — bookkeeping shows ~27 µs win): halves the per-wave serial
// gather chain (16B/lane/edge) and VGPR footprint -> 2x TLP for latency hiding.
// p = exp(lrelu(a_s[src]+a_d[dst])) recomputed per wave (cheap, head-uniform).
__device__ inline float lrelu(float v) { return v > 0.f ? v : NEG_SLOPE * v; }

__global__ __launch_bounds__(256)
void gat_aggregate(const int* __restrict__ offs, const int* __restrict__ deg_a,
                   const int* __restrict__ csr_src,
                   const float* __restrict__ a_s, const float* __restrict__ a_d,
                   const bf16* __restrict__ h, bf16* __restrict__ xg, int ldx)
{
  const int t = threadIdx.x;
  const int lane = t & 63;
  const int wave = t >> 6;
  const int ds = wave >> 1;            // 0..1: which dst in this block
  const int half = wave & 1;           // 0..1: which 512-channel half
  // XCD swizzle: graph b pinned to XCD b%8 (2 graphs = 4MB h per XCD L2)
  const int i = blockIdx.x;            // M_/2 blocks = 8 (xcd) x 512 (grp) x 2 (hi)
  const int b = (i & 7) + 8 * ((i >> 3) >> 9);
  const int grp = (i >> 3) & 511;
  const int bd = b * L_ + grp * 2 + ds;
  const int deg = deg_a[bd];
  const int* list = csr_src + (long)b * ET_ + offs[bd];
  const int c0 = half * 512 + lane * 8;  // my 8 channels
  const int hd = c0 >> 8;                // my head

  const float ad = a_d[(long)bd * H_ + hd];
  const float* asb = a_s + (long)b * L_ * H_ + hd;   // graph-local rebase

  float acc[8];
#pragma unroll
  for (int k = 0; k < 8; k++) acc[k] = 0.f;
  float ssum = 0.f;
  const bf16* hb = h + (long)b * L_ * HC_ + c0;

  if (deg <= 64) {
    int s_lane = (lane < deg) ? list[lane] : 0;
#pragma unroll 4
    for (int e = 0; e < deg; e++) {
      int se = __shfl(s_lane, e);
      uint4 u0 = *(const uint4*)(hb + (long)se * HC_);
      float as = asb[(long)se * H_];
      float p = __expf(lrelu(as + ad));
      float f[8];
      unpack8(u0, f);
      ssum += p;
#pragma unroll
      for (int k = 0; k < 8; k++) acc[k] += p * f[k];
    }
  } else {
    for (int e = 0; e < deg; e++) {
      int se = list[e];
      uint4 u0 = *(const uint4*)(hb + (long)se * HC_);
      float as = asb[(long)se * H_];
      float p = __expf(lrelu(as + ad));
      float f[8];
      unpack8(u0, f);
      ssum += p;
#pragma unroll
      for (int k = 0; k < 8; k++) acc[k] += p * f[k];
    }
  }

  float rs = 1.f / (ssum + 1e-16f);
  bf16 ov[8];
#pragma unroll
  for (int k = 0; k < 8; k++) ov[k] = __float2bfloat16(acc[k] * rs);
  bf16* op = xg + (long)bd * ldx + c0;
  *(uint4*)op = *(const uint4*)ov;
}

// ---------------- launch ----------------
extern "C" void kernel_launch(void* const* d_in, const int* in_sizes, int n_in,
                              void* d_out, int out_size, void* d_ws, size_t ws_size,
                              hipStream_t stream) {
  const float* x     = (const float*)d_in[0];
  const int*   ei    = (const int*)d_in[1];
  const float* Wg    = (const float*)d_in[2];
  const float* att_s = (const float*)d_in[3];
  const float* att_d = (const float*)d_in[4];
  const float* bgat  = (const float*)d_in[5];
  const float* Wout  = (const float*)d_in[6];
  const float* bout  = (const float*)d_in[7];
  float* out = (float*)d_out;

  char* ws = (char*)d_ws;
  size_t off = 0;
  auto alloc = [&](size_t bytes) {
    void* p = ws + off;
    off = (off + bytes + 255) & ~(size_t)255;
    return p;
  };
  bf16* xf      = (bf16*)alloc((size_t)M_ * F_ * 2);       // 56 MB: [x | xg] bf16
  bf16* wg_bf   = (bf16*)alloc((size_t)HC_ * D_ * 2);
  bf16* wout_bf = (bf16*)alloc((size_t)D_ * F_ * 2);
  bf16* h_bf    = (bf16*)alloc((size_t)M_ * HC_ * 2);      // 32 MB
  int* deg      = (int*)alloc((size_t)M_ * 4);
  int* offs     = (int*)alloc((size_t)M_ * 4);
  int* csr_src  = (int*)alloc((size_t)B_ * ET_ * 4);
  float* cout   = (float*)alloc((size_t)D_ * 4);
  float* a_s    = (float*)alloc((size_t)M_ * H_ * 4);      // 256 KB
  float* a_d    = (float*)alloc((size_t)M_ * H_ * 4);      // 256 KB

  // 1. prep: CSR + x cast + weight casts + cout — one dispatch
  prep<<<dim3(NB_CSR + NB_X + NB_W + NB_CO), dim3(256), 0, stream>>>(
      x, ei, Wg, Wout, bgat, bout, xf, wg_bf, wout_bf, deg, offs, csr_src, cout);

  // 2. h = x @ Wg^T (bf16 out)   — 128 x 8 = 1024 blocks
  gemm_nt_128<1><<<dim3(M_ / BM, HC_ / BN), dim3(256), 0, stream>>>(
      xf, F_, wg_bf, D_, h_bf, HC_, D_, nullptr);

  // 3a. per-node attention logit halves (standalone — round-5 fusion regressed)
  calc_asd<<<dim3(M_ / 4), dim3(256), 0, stream>>>(h_bf, att_s, att_d, a_s, a_d);

  // 3b. fused softmax + aggregate (2 waves per node), writes xg columns of xf
  gat_aggregate<<<dim3(M_ / 2), dim3(256), 0, stream>>>(offs, deg, csr_src,
                                                        a_s, a_d, h_bf, xf + D_, F_);

  // 4. out = [x|xg] @ W_out^T + cout   (single K=1792 GEMM) — 128 x 6 = 768 blocks
  gemm_nt_128<0><<<dim3(M_ / BM, D_ / BN), dim3(256), 0, stream>>>(
      xf, F_, wout_bf, F_, out, D_, F_, cout);
}